// Round 1
// baseline (164.202 us; speedup 1.0000x reference)
//
#include <hip/hip_runtime.h>
#include <math.h>

#define BATCH 64
#define DIM 512
#define NPATCH 128
#define SSZ 64
#define NMASK 1152   // P*9
#define NTHETA 768   // P*6
#define NROWS 1920   // NMASK + NTHETA

// ---------------------------------------------------------------------------
// Kernel 1: tmp[j*64 + b] for j in [0,1920)
//   j < 1152 : (1 - sigmoid(z[b].Wm[j] + bm[j])) * noise[j%9]
//   j >= 1152: z[b].Wt[j-1152] + bt[j-1152]
// Block tile: all 64 batches x 16 rows. 120 blocks, 256 threads.
// ---------------------------------------------------------------------------
__global__ __launch_bounds__(256) void k1_gemm(
    const float* __restrict__ z, const float* __restrict__ Wm,
    const float* __restrict__ bm, const float* __restrict__ Wt,
    const float* __restrict__ bt, const float* __restrict__ noise,
    float* __restrict__ tmp) {
  // zs padded to 65: compute read zs[b][k] with b = lane -> bank (b+k)%32,
  // 2 lanes/bank (b, b+32) = free 2-way. ws rows are wave-uniform -> broadcast.
  __shared__ float zs[64][65];
  __shared__ float ws[16][64];

  const int t = threadIdx.x;
  const int rowBase = blockIdx.x * 16;
  const int b = t & 63;      // batch handled by this thread
  const int rgrp = t >> 6;   // 0..3 (wave-uniform)

  float acc0 = 0.f, acc1 = 0.f, acc2 = 0.f, acc3 = 0.f;

  // staging roles
  const int zb = t >> 2, zseg = t & 3;     // z loader: row zb, 16-col segment
  const int wrow = t >> 4, wseg = t & 15;  // W loader: row wrow, 4-col segment
  const int j_w = rowBase + wrow;
  const float* wsrc = (j_w < NMASK) ? (Wm + (size_t)j_w * DIM)
                                    : (Wt + (size_t)(j_w - NMASK) * DIM);

  for (int kc = 0; kc < DIM; kc += 64) {
    __syncthreads();  // previous chunk's compute done before overwrite
    // stage z chunk: 64 rows x 64 cols
    {
      const float4* zsrc4 = (const float4*)(z + (size_t)zb * DIM + kc + zseg * 16);
      float* zd = &zs[zb][zseg * 16];
#pragma unroll
      for (int u = 0; u < 4; ++u) {
        float4 a = zsrc4[u];
        zd[u * 4 + 0] = a.x; zd[u * 4 + 1] = a.y;
        zd[u * 4 + 2] = a.z; zd[u * 4 + 3] = a.w;
      }
    }
    // stage W chunk: 16 rows x 64 cols
    {
      float4 wv = *(const float4*)(wsrc + kc + wseg * 4);
      *(float4*)&ws[wrow][wseg * 4] = wv;
    }
    __syncthreads();
#pragma unroll 8
    for (int k = 0; k < 64; ++k) {
      float zv = zs[b][k];
      acc0 = fmaf(zv, ws[rgrp * 4 + 0][k], acc0);
      acc1 = fmaf(zv, ws[rgrp * 4 + 1][k], acc1);
      acc2 = fmaf(zv, ws[rgrp * 4 + 2][k], acc2);
      acc3 = fmaf(zv, ws[rgrp * 4 + 3][k], acc3);
    }
  }

  float accs[4] = {acc0, acc1, acc2, acc3};
#pragma unroll
  for (int rr = 0; rr < 4; ++rr) {
    int j = rowBase + rgrp * 4 + rr;
    float v = accs[rr];
    if (j < NMASK) {
      // 1 - sigmoid(x) = 1/(1+exp(x))
      v = 1.0f / (1.0f + expf(v + bm[j]));
      v *= noise[j % 9];
    } else {
      v += bt[j - NMASK];
    }
    tmp[(size_t)j * 64 + b] = v;  // coalesced over b (lane)
  }
}

// ---------------------------------------------------------------------------
// Kernel 2: one block per (b,p) image. 3x3 mask placed in a zero-padded 7x8
// LDS tile -> bilinear-with-zeros needs no validity logic at all.
// Coordinates clamped to [-1.5, 3.5]: any clamped sample has both taps in the
// zero halo (valid taps need ix in (-1,3)), so output is 0 either way.
// 256 threads x 16 pixels; w = t&63 constant per thread -> 2 FMA per pixel
// for the full affine-grid + unnormalize chain.
// ---------------------------------------------------------------------------
__global__ __launch_bounds__(256) void k2_sample(
    const float* __restrict__ tmp, float* __restrict__ out) {
  __shared__ float msp[56];  // [7 rows][8 cols], mask at rows/cols 2..4
  __shared__ float ths[6];

  const int t = threadIdx.x;
  const int bp = blockIdx.x;      // 0..8191
  const int b = bp >> 7;
  const int p = bp & 127;

  if (t < 56) {
    int r = t >> 3, c = t & 7;
    float v = 0.0f;
    if (r >= 2 && r <= 4 && c >= 2 && c <= 4) {
      int q = (r - 2) * 3 + (c - 2);
      v = tmp[(size_t)(p * 9 + q) * 64 + b];
    }
    msp[t] = v;
  } else if (t < 62) {
    ths[t - 56] = tmp[(size_t)(NMASK + p * 6 + (t - 56)) * 64 + b];
  }
  __syncthreads();

  const float th0 = ths[0], th1 = ths[1], th2 = ths[2];
  const float th3 = ths[3], th4 = ths[4], th5 = ths[5];

  const int w = t & 63;
  const float cx = (w + 0.5f) * (1.0f / 32.0f) - 1.0f;
  // ix = 1.5*(th0*cx + th1*cy + th2) + 1  ->  fma(Bx, cy, A)
  const float A  = fmaf(1.5f, fmaf(th0, cx, th2), 1.0f);
  const float Bx = 1.5f * th1;
  const float C  = fmaf(1.5f, fmaf(th3, cx, th5), 1.0f);
  const float By = 1.5f * th4;

  float* obase = out + ((size_t)bp << 12) + t;
  const int h0 = t >> 6;

#pragma unroll
  for (int i = 0; i < 16; ++i) {
    const int h = h0 + i * 4;
    const float cy = (h + 0.5f) * (1.0f / 32.0f) - 1.0f;
    float ix = fmaf(Bx, cy, A);
    float iy = fmaf(By, cy, C);
    ix = fminf(fmaxf(ix, -1.5f), 3.5f);
    iy = fminf(fmaxf(iy, -1.5f), 3.5f);
    float fx0 = floorf(ix);
    float fy0 = floorf(iy);
    float fx = ix - fx0;
    float fy = iy - fy0;
    int xi = (int)fx0;   // in [-2, 3]
    int yi = (int)fy0;   // in [-2, 3]
    int idx = (yi + 2) * 8 + (xi + 2);   // flat index into msp, taps all in-range
    float v00 = msp[idx];
    float v01 = msp[idx + 1];
    float v10 = msp[idx + 8];
    float v11 = msp[idx + 9];
    float wx0 = 1.0f - fx;
    float t0 = fmaf(fx, v01, wx0 * v00);
    float t1 = fmaf(fx, v11, wx0 * v10);
    float r  = fmaf(fy, t1, (1.0f - fy) * t0);
    obase[(size_t)i * 256] = r;  // lanes consecutive -> coalesced 1KB/instr
  }
}

extern "C" void kernel_launch(void* const* d_in, const int* in_sizes, int n_in,
                              void* d_out, int out_size, void* d_ws, size_t ws_size,
                              hipStream_t stream) {
  const float* z     = (const float*)d_in[0];
  const float* Wm    = (const float*)d_in[1];
  const float* bm    = (const float*)d_in[2];
  const float* Wt    = (const float*)d_in[3];
  const float* bt    = (const float*)d_in[4];
  const float* noise = (const float*)d_in[5];
  float* out = (float*)d_out;
  float* tmp = (float*)d_ws;  // 1920*64 floats = 480 KB

  hipLaunchKernelGGL(k1_gemm, dim3(NROWS / 16), dim3(256), 0, stream,
                     z, Wm, bm, Wt, bt, noise, tmp);
  hipLaunchKernelGGL(k2_sample, dim3(BATCH * NPATCH), dim3(256), 0, stream,
                     tmp, out);
}

// Round 2
// 162.494 us; speedup vs baseline: 1.0105x; 1.0105x over previous
//
#include <hip/hip_runtime.h>
#include <math.h>

#define BATCH 64
#define DIM 512
#define NPATCH 128
#define SSZ 64
#define NMASK 1152   // P*9
#define NTHETA 768   // P*6
#define NROWS 1920   // NMASK + NTHETA

// ---------------------------------------------------------------------------
// Kernel 1: tmp[j*64 + b] for j in [0,1920)
//   j < 1152 : (1 - sigmoid(z[b].Wm[j] + bm[j])) * noise[j%9]
//   j >= 1152: z[b].Wt[j-1152] + bt[j-1152]
// Block tile: all 64 batches x 16 rows. 120 blocks, 256 threads.
// ---------------------------------------------------------------------------
__global__ __launch_bounds__(256) void k1_gemm(
    const float* __restrict__ z, const float* __restrict__ Wm,
    const float* __restrict__ bm, const float* __restrict__ Wt,
    const float* __restrict__ bt, const float* __restrict__ noise,
    float* __restrict__ tmp) {
  // zs padded to 65: compute reads zs[b][k] with b = lane -> 2 lanes/bank = free.
  // ws rows are wave-uniform -> broadcast.
  __shared__ float zs[64][65];
  __shared__ float ws[16][64];

  const int t = threadIdx.x;
  const int rowBase = blockIdx.x * 16;
  const int b = t & 63;      // batch handled by this thread
  const int rgrp = t >> 6;   // 0..3 (wave-uniform)

  float acc0 = 0.f, acc1 = 0.f, acc2 = 0.f, acc3 = 0.f;

  // staging roles
  const int zb = t >> 2, zseg = t & 3;     // z loader: row zb, 16-col segment
  const int wrow = t >> 4, wseg = t & 15;  // W loader: row wrow, 4-col segment
  const int j_w = rowBase + wrow;
  const float* wsrc = (j_w < NMASK) ? (Wm + (size_t)j_w * DIM)
                                    : (Wt + (size_t)(j_w - NMASK) * DIM);

  for (int kc = 0; kc < DIM; kc += 64) {
    __syncthreads();  // previous chunk's compute done before overwrite
    // stage z chunk: 64 rows x 64 cols
    {
      const float4* zsrc4 = (const float4*)(z + (size_t)zb * DIM + kc + zseg * 16);
      float* zd = &zs[zb][zseg * 16];
#pragma unroll
      for (int u = 0; u < 4; ++u) {
        float4 a = zsrc4[u];
        zd[u * 4 + 0] = a.x; zd[u * 4 + 1] = a.y;
        zd[u * 4 + 2] = a.z; zd[u * 4 + 3] = a.w;
      }
    }
    // stage W chunk: 16 rows x 64 cols
    {
      float4 wv = *(const float4*)(wsrc + kc + wseg * 4);
      *(float4*)&ws[wrow][wseg * 4] = wv;
    }
    __syncthreads();
#pragma unroll 8
    for (int k = 0; k < 64; ++k) {
      float zv = zs[b][k];
      acc0 = fmaf(zv, ws[rgrp * 4 + 0][k], acc0);
      acc1 = fmaf(zv, ws[rgrp * 4 + 1][k], acc1);
      acc2 = fmaf(zv, ws[rgrp * 4 + 2][k], acc2);
      acc3 = fmaf(zv, ws[rgrp * 4 + 3][k], acc3);
    }
  }

  float accs[4] = {acc0, acc1, acc2, acc3};
#pragma unroll
  for (int rr = 0; rr < 4; ++rr) {
    int j = rowBase + rgrp * 4 + rr;
    float v = accs[rr];
    if (j < NMASK) {
      // 1 - sigmoid(x) = 1/(1+exp(x))
      v = 1.0f / (1.0f + expf(v + bm[j]));
      v *= noise[j % 9];
    } else {
      v += bt[j - NMASK];
    }
    tmp[(size_t)j * 64 + b] = v;  // coalesced over b (lane)
  }
}

// ---------------------------------------------------------------------------
// Kernel 2: one block per (b,p) image. Bilinear-with-zeros over a 3x3 mask
// expressed in the tensor-product hat basis:
//   out(ix,iy) = sum_{y,x in 0..2} m[y][x] * hat(iy-y) * hat(ix-x),
//   hat(t) = max(0, 1-|t|).
// No LDS taps, no floor/int-cvt, no bounds logic — zeros padding is the hat
// support. Mask (9) + theta (6) are block-uniform, broadcast via LDS once.
// 256 threads; each thread owns 4 consecutive w and 4 rows -> 4 float4 stores;
// a wave's store covers a contiguous 1 KiB.
// ---------------------------------------------------------------------------
__global__ __launch_bounds__(256) void k2_sample(
    const float* __restrict__ tmp, float* __restrict__ out) {
  __shared__ float sm[15];  // 9 mask + 6 theta

  const int t = threadIdx.x;
  const int bp = blockIdx.x;      // 0..8191
  const int b = bp >> 7;
  const int p = bp & 127;

  if (t < 9) {
    sm[t] = tmp[(size_t)(p * 9 + t) * 64 + b];
  } else if (t < 15) {
    sm[t] = tmp[(size_t)(NMASK + p * 6 + (t - 9)) * 64 + b];
  }
  __syncthreads();

  const float m00 = sm[0], m01 = sm[1], m02 = sm[2];
  const float m10 = sm[3], m11 = sm[4], m12 = sm[5];
  const float m20 = sm[6], m21 = sm[7], m22 = sm[8];
  const float th0 = sm[9], th1 = sm[10], th2 = sm[11];
  const float th3 = sm[12], th4 = sm[13], th5 = sm[14];

  const int w4 = (t & 15) << 2;   // 4 consecutive w per thread
  const int hb = t >> 4;          // base row 0..15
  const float cx0 = (w4 + 0.5f) * (1.0f / 32.0f) - 1.0f;
  const float cy0 = (hb + 0.5f) * (1.0f / 32.0f) - 1.0f;
  // ix = 1.5*(th0*cx + th1*cy + th2) + 1 ; per-w step:
  const float dix = th0 * (1.5f / 32.0f);
  const float diy = th3 * (1.5f / 32.0f);
  const float Bx = 1.5f * th1, By = 1.5f * th4;
  const float Px = fmaf(1.5f, fmaf(th0, cx0, th2), 1.0f);
  const float Py = fmaf(1.5f, fmaf(th3, cx0, th5), 1.0f);

  float* op = out + ((size_t)bp << 12) + hb * 64 + w4;

#pragma unroll
  for (int i = 0; i < 4; ++i) {
    const float cy = cy0 + 0.5f * i;      // row hb + 16*i
    float ix = fmaf(Bx, cy, Px);
    float iy = fmaf(By, cy, Py);
    float4 r;
    float* rp = &r.x;
#pragma unroll
    for (int j = 0; j < 4; ++j) {
      const float wx0 = fmaxf(1.0f - fabsf(ix), 0.0f);
      const float wx1 = fmaxf(1.0f - fabsf(ix - 1.0f), 0.0f);
      const float wx2 = fmaxf(1.0f - fabsf(ix - 2.0f), 0.0f);
      const float wy0 = fmaxf(1.0f - fabsf(iy), 0.0f);
      const float wy1 = fmaxf(1.0f - fabsf(iy - 1.0f), 0.0f);
      const float wy2 = fmaxf(1.0f - fabsf(iy - 2.0f), 0.0f);
      const float s0 = fmaf(m02, wx2, fmaf(m01, wx1, m00 * wx0));
      const float s1 = fmaf(m12, wx2, fmaf(m11, wx1, m10 * wx0));
      const float s2 = fmaf(m22, wx2, fmaf(m21, wx1, m20 * wx0));
      rp[j] = fmaf(wy2, s2, fmaf(wy1, s1, wy0 * s0));
      ix += dix;
      iy += diy;
    }
    *(float4*)(op + i * 16 * 64) = r;  // rows hb, hb+16, hb+32, hb+48
  }
}

extern "C" void kernel_launch(void* const* d_in, const int* in_sizes, int n_in,
                              void* d_out, int out_size, void* d_ws, size_t ws_size,
                              hipStream_t stream) {
  const float* z     = (const float*)d_in[0];
  const float* Wm    = (const float*)d_in[1];
  const float* bm    = (const float*)d_in[2];
  const float* Wt    = (const float*)d_in[3];
  const float* bt    = (const float*)d_in[4];
  const float* noise = (const float*)d_in[5];
  float* out = (float*)d_out;
  float* tmp = (float*)d_ws;  // 1920*64 floats = 480 KB

  hipLaunchKernelGGL(k1_gemm, dim3(NROWS / 16), dim3(256), 0, stream,
                     z, Wm, bm, Wt, bt, noise, tmp);
  hipLaunchKernelGGL(k2_sample, dim3(BATCH * NPATCH), dim3(256), 0, stream,
                     tmp, out);
}

// Round 3
// 161.192 us; speedup vs baseline: 1.0187x; 1.0081x over previous
//
#include <hip/hip_runtime.h>
#include <math.h>

#define BATCH 64
#define DIM 512
#define NPATCH 128
#define SSZ 64

// ---------------------------------------------------------------------------
// Fully fused: one block per (b,p) image, 256 threads.
//
// Phase 1 (GEMM slice): 15 output rows for this (b,p) — 9 mask logits
//   (1-sigmoid)*noise and 6 theta entries. 16 threads per row, 32 dims each,
//   float4 loads (each 16-lane row-group reads 256 B contiguous), shfl_xor
//   tree reduce, epilogue on lane 0, broadcast through 15-word LDS.
//   Total MACs across grid = 1920*64*512 — identical to a standalone GEMM,
//   just distributed; W (3.9 MB) lives in each XCD's 4 MiB L2.
//
// Phase 2 (sampler): bilinear-with-zeros over the 3x3 mask in the
//   tensor-product hat basis: out = sum m[y][x]*hat(iy-y)*hat(ix-x),
//   hat(t)=max(0,1-|t|). No taps, no bounds logic. Each thread owns
//   4 consecutive w and 4 rows -> 4 float4 stores; a wave's store is a
//   contiguous 1 KiB.
// ---------------------------------------------------------------------------
__global__ __launch_bounds__(256) void k_fused(
    const float* __restrict__ z, const float* __restrict__ Wm,
    const float* __restrict__ bm, const float* __restrict__ Wt,
    const float* __restrict__ bt, const float* __restrict__ noise,
    float* __restrict__ out) {
  __shared__ float sm[16];  // 9 mask + 6 theta (+1 pad)

  const int t = threadIdx.x;
  const int bp = blockIdx.x;      // 0..8191
  const int b = bp >> 7;
  const int p = bp & 127;

  // ---- Phase 1: 15 dot products of length 512 ----
  const int r = t >> 4;   // 0..15 (row; 15 idle)
  const int c = t & 15;   // lane within row-group
  float acc = 0.0f;
  if (r < 15) {
    const float* __restrict__ wrow =
        (r < 9) ? (Wm + (size_t)(p * 9 + r) * DIM)
                : (Wt + (size_t)(p * 6 + (r - 9)) * DIM);
    const float* __restrict__ zrow = z + (size_t)b * DIM;
#pragma unroll
    for (int i = 0; i < 8; ++i) {
      const float4 wv = *(const float4*)(wrow + i * 64 + c * 4);
      const float4 zv = *(const float4*)(zrow + i * 64 + c * 4);
      acc = fmaf(wv.x, zv.x, acc);
      acc = fmaf(wv.y, zv.y, acc);
      acc = fmaf(wv.z, zv.z, acc);
      acc = fmaf(wv.w, zv.w, acc);
    }
  }
  // reduce within each 16-lane group
  acc += __shfl_xor(acc, 1);
  acc += __shfl_xor(acc, 2);
  acc += __shfl_xor(acc, 4);
  acc += __shfl_xor(acc, 8);
  if (c == 0 && r < 15) {
    float v = acc;
    if (r < 9) {
      // 1 - sigmoid(x) = 1/(1+exp(x)), then patch noise
      v = (1.0f / (1.0f + expf(v + bm[p * 9 + r]))) * noise[r];
    } else {
      v += bt[p * 6 + (r - 9)];
    }
    sm[r] = v;
  }
  __syncthreads();

  // ---- Phase 2: sampler ----
  const float m00 = sm[0], m01 = sm[1], m02 = sm[2];
  const float m10 = sm[3], m11 = sm[4], m12 = sm[5];
  const float m20 = sm[6], m21 = sm[7], m22 = sm[8];
  const float th0 = sm[9], th1 = sm[10], th2 = sm[11];
  const float th3 = sm[12], th4 = sm[13], th5 = sm[14];

  const int w4 = (t & 15) << 2;   // 4 consecutive w per thread
  const int hb = t >> 4;          // base row 0..15
  const float cx0 = (w4 + 0.5f) * (1.0f / 32.0f) - 1.0f;
  const float cy0 = (hb + 0.5f) * (1.0f / 32.0f) - 1.0f;
  // ix = 1.5*(th0*cx + th1*cy + th2) + 1
  const float dix = th0 * (1.5f / 32.0f);  // per-w step
  const float diy = th3 * (1.5f / 32.0f);
  const float Bx = 1.5f * th1, By = 1.5f * th4;
  const float Px = fmaf(1.5f, fmaf(th0, cx0, th2), 1.0f);
  const float Py = fmaf(1.5f, fmaf(th3, cx0, th5), 1.0f);

  float* op = out + ((size_t)bp << 12) + hb * 64 + w4;

#pragma unroll
  for (int i = 0; i < 4; ++i) {
    const float cy = cy0 + 0.5f * i;      // row hb + 16*i
    float ix = fmaf(Bx, cy, Px);
    float iy = fmaf(By, cy, Py);
    float4 rv;
    float* rp = &rv.x;
#pragma unroll
    for (int j = 0; j < 4; ++j) {
      const float wx0 = fmaxf(1.0f - fabsf(ix), 0.0f);
      const float wx1 = fmaxf(1.0f - fabsf(ix - 1.0f), 0.0f);
      const float wx2 = fmaxf(1.0f - fabsf(ix - 2.0f), 0.0f);
      const float wy0 = fmaxf(1.0f - fabsf(iy), 0.0f);
      const float wy1 = fmaxf(1.0f - fabsf(iy - 1.0f), 0.0f);
      const float wy2 = fmaxf(1.0f - fabsf(iy - 2.0f), 0.0f);
      const float s0 = fmaf(m02, wx2, fmaf(m01, wx1, m00 * wx0));
      const float s1 = fmaf(m12, wx2, fmaf(m11, wx1, m10 * wx0));
      const float s2 = fmaf(m22, wx2, fmaf(m21, wx1, m20 * wx0));
      rp[j] = fmaf(wy2, s2, fmaf(wy1, s1, wy0 * s0));
      ix += dix;
      iy += diy;
    }
    *(float4*)(op + i * 16 * 64) = rv;  // rows hb, hb+16, hb+32, hb+48
  }
}

extern "C" void kernel_launch(void* const* d_in, const int* in_sizes, int n_in,
                              void* d_out, int out_size, void* d_ws, size_t ws_size,
                              hipStream_t stream) {
  const float* z     = (const float*)d_in[0];
  const float* Wm    = (const float*)d_in[1];
  const float* bm    = (const float*)d_in[2];
  const float* Wt    = (const float*)d_in[3];
  const float* bt    = (const float*)d_in[4];
  const float* noise = (const float*)d_in[5];
  float* out = (float*)d_out;

  hipLaunchKernelGGL(k_fused, dim3(BATCH * NPATCH), dim3(256), 0, stream,
                     z, Wm, bm, Wt, bt, noise, out);
}